// Round 1
// 381.654 us; speedup vs baseline: 1.0186x; 1.0186x over previous
//
#include <hip/hip_runtime.h>
#include <math.h>

// EncoderBlock: B=8, N=1024, EMB=768, HEADS=8, DHEAD=96
// R9: replace the 128x128 2-barrier GEMM (measured ~570 TF, vmcnt(0)-drain
//     structure-bound) with a 256x128-tile, 8-wave, TRIPLE-buffered 8-phase
//     pipeline (T3+T4+T5 from the catalog):
//       - per K-tile: 2 phases of {8 ds_read_b128 frags | 3 global_load_lds
//         prefetch of tile g+2 -> s_barrier -> setprio(1)+16 MFMA+setprio(0)
//         -> sched_barrier(0) -> s_barrier}
//       - s_waitcnt vmcnt(6) once per K-tile (never 0 in main loop); triple
//         buffer makes the slot for tile g+2 dead from group-g start, so
//         loads stay in flight ~2 groups (> HBM latency).
//       - XOR-8 pre-swizzled-source staging kept (0 bank conflicts measured).
//       - bijective XCD M-stripe grid swizzle (A-panel 1.5MB stays L2-resident).
//     All four GEMMs (QKVR / PROJ / FF1-GELU / FF2) use the new kernel.
//     Attention / LN / transposes unchanged.

typedef __bf16 bf16_t;
typedef __bf16 bf16x4 __attribute__((ext_vector_type(4)));
typedef __bf16 bf16x8 __attribute__((ext_vector_type(8)));
typedef float f32x4 __attribute__((ext_vector_type(4)));

#define EMB   768
#define HEADS 8
#define DHEAD 96
#define BATCH 8
#define SEQ   1024
#define ROWS  (BATCH * SEQ)   // 8192

__device__ __forceinline__ void load16_lds(const bf16_t* g, bf16_t* l) {
    __builtin_amdgcn_global_load_lds(
        (__attribute__((address_space(1))) unsigned int*)g,
        (__attribute__((address_space(3))) unsigned int*)l,
        16, 0, 0);
}

// ---------------------------------------------------------------- conversions

__global__ void cvt_bf16_kernel(const float* __restrict__ in, bf16_t* __restrict__ out, int n) {
    int stride = gridDim.x * blockDim.x;
    for (int i = blockIdx.x * blockDim.x + threadIdx.x; i < n; i += stride)
        out[i] = (bf16_t)in[i];
}

// in: [K][N] fp32 row-major  ->  out: [N][K] bf16 row-major (B^T for GEMMs)
__global__ void transpose_cvt_kernel(const float* __restrict__ in, bf16_t* __restrict__ out,
                                     int K, int N) {
    __shared__ float t[32][33];
    int n0 = blockIdx.x * 32, k0 = blockIdx.y * 32;
    int tx = threadIdx.x, ty0 = threadIdx.y;  // block (32,8)
#pragma unroll
    for (int i = 0; i < 4; i++) {
        int ty = ty0 + 8 * i;
        t[ty][tx] = in[(size_t)(k0 + ty) * N + n0 + tx];
    }
    __syncthreads();
#pragma unroll
    for (int i = 0; i < 4; i++) {
        int ty = ty0 + 8 * i;
        out[(size_t)(n0 + ty) * K + k0 + tx] = (bf16_t)t[tx][ty];
    }
}

// w_qkvr [768][3072] -> wqkvrT [3072][768] bf16 with COLUMN PERMUTATION:
// output row n' = which*768 + hd  <-  source column hd*4 + which.
__global__ void qkvr_transpose_kernel(const float* __restrict__ in, bf16_t* __restrict__ out) {
    __shared__ float t[32][33];
    int n0 = blockIdx.x * 32, k0 = blockIdx.y * 32;
    int tx = threadIdx.x, ty0 = threadIdx.y;  // block (32,8)
    const int which = n0 / 768, hd0 = n0 % 768;
#pragma unroll
    for (int i = 0; i < 4; i++) {
        int ty = ty0 + 8 * i;
        t[ty][tx] = in[(size_t)(k0 + ty) * 3072 + (hd0 + tx) * 4 + which];
    }
    __syncthreads();
#pragma unroll
    for (int i = 0; i < 4; i++) {
        int ty = ty0 + 8 * i;
        out[(size_t)(n0 + ty) * 768 + k0 + tx] = (bf16_t)t[tx][ty];
    }
}

// ---------------------------------------------------------------- GEMM (bf16 MFMA, 8-phase)
// C[M,N] = A[M,K] @ BT[N,K]^T + bias. Tile 256x128, BK=64, 512 thr = 8 waves
// as 4(M)x2(N); per-wave C = 64x64 -> acc[4][4] of 16x16 frags.
// LDS: 3 buffers x (A 32KB + B 16KB) = 144 KiB -> 1 block/CU, 2 waves/SIMD.
// Pipeline: group g computes buf[g%3]; stages tile g+2 into buf[(g+2)%3]
// (tenant g-1 died at group-(g-1) end barrier -> slot dead for whole group g).
// vmcnt(6) at end of group g gates tile g+1's 6 loads (issued in group g-1).

enum { EPI_QKVR = 0, EPI_PROJ = 1, EPI_GELU = 2, EPI_FF2 = 3 };

template <int EPI, int KDIM, int NBX>
__global__ __launch_bounds__(512, 2) void gemm8p_kernel(
    const bf16_t* __restrict__ A,    // [M,KDIM]
    const bf16_t* __restrict__ BT,   // [N,KDIM]
    const float* __restrict__ bias,  // [N] (EPI_QKVR: original qkvr order)
    bf16_t* __restrict__ qo, bf16_t* __restrict__ ko,
    bf16_t* __restrict__ vTo, bf16_t* __restrict__ ro,   // EPI_QKVR outputs
    const float* __restrict__ resid,                     // EPI_PROJ / EPI_FF2 residual
    float* __restrict__ outf,                            // EPI_PROJ / EPI_FF2 fp32 out
    bf16_t* __restrict__ outb)                           // EPI_GELU bf16 out
{
    constexpr int NKT  = KDIM / 64;   // K-tiles
    constexpr int BUFE = 24576;       // elems per buffer: A 16384 + B 8192

    __shared__ __align__(16) bf16_t lds[3 * BUFE];  // 144 KiB

    const int tid  = threadIdx.x;
    const int wave = tid >> 6, lane = tid & 63;
    const int quad = lane >> 4, col16 = lane & 15;
    const int wm = wave >> 1, wn = wave & 1;        // 4(M) x 2(N) waves

    // bijective XCD swizzle: XCD x owns a contiguous M-stripe (bx fastest)
    const int cpx  = gridDim.x >> 3;
    const int id   = blockIdx.x;
    const int wgid = (id & 7) * cpx + (id >> 3);
    const int bx = wgid % NBX, by = wgid / NBX;
    const int m0 = by * 256, n0 = bx * 128;

    // staging maps: 16B unit u -> row=u>>3, slot=u&7, global k-unit j=slot^(row&7).
    // LDS dst lane-contiguous (global_load_lds constraint); swizzle on the source.
    size_t gA[4]; int lA[4];
    size_t gB[2]; int lB[2];
#pragma unroll
    for (int i = 0; i < 4; i++) {
        const int u = tid + 512 * i;
        const int r = u >> 3, j = (u & 7) ^ (r & 7);
        gA[i] = (size_t)(m0 + r) * KDIM + j * 8;
        lA[i] = u * 8;
    }
#pragma unroll
    for (int i = 0; i < 2; i++) {
        const int u = tid + 512 * i;
        const int r = u >> 3, j = (u & 7) ^ (r & 7);
        gB[i] = (size_t)(n0 + r) * KDIM + j * 8;
        lB[i] = 16384 + u * 8;
    }

#define STAGE_H0(g_, buf_) do { \
        const int k0_ = (g_) * 64; \
        load16_lds(A  + gA[0] + k0_, lds + (buf_) * BUFE + lA[0]); \
        load16_lds(A  + gA[1] + k0_, lds + (buf_) * BUFE + lA[1]); \
        load16_lds(BT + gB[0] + k0_, lds + (buf_) * BUFE + lB[0]); \
    } while (0)
#define STAGE_H1(g_, buf_) do { \
        const int k0_ = (g_) * 64; \
        load16_lds(A  + gA[2] + k0_, lds + (buf_) * BUFE + lA[2]); \
        load16_lds(A  + gA[3] + k0_, lds + (buf_) * BUFE + lA[3]); \
        load16_lds(BT + gB[1] + k0_, lds + (buf_) * BUFE + lB[1]); \
    } while (0)

    // prologue: tiles 0 and 1 in flight; gate tile 0 (oldest 6), counted wait.
    STAGE_H0(0, 0); STAGE_H1(0, 0);
    STAGE_H0(1, 1); STAGE_H1(1, 1);
    asm volatile("s_waitcnt vmcnt(6)" ::: "memory");
    __builtin_amdgcn_s_barrier();

    f32x4 acc[4][4] = {};

#pragma unroll 3
    for (int g = 0; g < NKT; g++) {
        const int buf  = g % 3;
        const int sbuf = (g + 2) % 3;
        const bf16_t* Ab = lds + buf * BUFE;
        const bf16_t* Bb = Ab + 16384;
        const bool do_stage = (g + 2 < NKT);
#pragma unroll
        for (int kc = 0; kc < 2; kc++) {
            bf16x8 af[4], bfr[4];
#pragma unroll
            for (int t = 0; t < 4; t++) {
                const int R = wm * 64 + t * 16 + col16;
                af[t] = *reinterpret_cast<const bf16x8*>(
                    Ab + R * 64 + (((kc * 4 + quad) ^ (R & 7)) * 8));
            }
#pragma unroll
            for (int t = 0; t < 4; t++) {
                const int S = wn * 64 + t * 16 + col16;
                bfr[t] = *reinterpret_cast<const bf16x8*>(
                    Bb + S * 64 + (((kc * 4 + quad) ^ (S & 7)) * 8));
            }
            if (kc == 0) {
                if (do_stage) STAGE_H0(g + 2, sbuf);
            } else {
                if (do_stage) {
                    STAGE_H1(g + 2, sbuf);
                    asm volatile("s_waitcnt vmcnt(6)" ::: "memory");  // tile g+1 landed
                } else if (g + 2 == NKT) {
                    asm volatile("s_waitcnt vmcnt(0)" ::: "memory");  // drain for last tile
                }
            }
            __builtin_amdgcn_s_barrier();
            __builtin_amdgcn_s_setprio(1);
#pragma unroll
            for (int tr = 0; tr < 4; tr++)
#pragma unroll
                for (int tc = 0; tc < 4; tc++)
                    acc[tr][tc] = __builtin_amdgcn_mfma_f32_16x16x32_bf16(
                        af[tr], bfr[tc], acc[tr][tc], 0, 0, 0);
            __builtin_amdgcn_s_setprio(0);
            __builtin_amdgcn_sched_barrier(0);  // pin MFMAs before the barrier (rule-18 class)
            __builtin_amdgcn_s_barrier();
        }
    }
#undef STAGE_H0
#undef STAGE_H1

    // ---------------- epilogues (row = m0+wm*64+tr*16+quad*4+rg, col = n0+wn*64+tc*16+col16)
    if (EPI == EPI_QKVR) {
        const int whichb = bx / 6;
        if (whichb == 2) {
            // V: transpose store, packed over 4 consecutive seq positions.
#pragma unroll
            for (int tr = 0; tr < 4; tr++) {
#pragma unroll
                for (int tc = 0; tc < 4; tc++) {
                    const int hd   = (bx % 6) * 128 + wn * 64 + tc * 16 + col16;
                    const int head = hd / DHEAD, dd = hd % DHEAD;
                    const float bv = bias[hd * 4 + 2];
                    const int row0 = m0 + wm * 64 + tr * 16 + quad * 4;
                    const int b = row0 >> 10, nn0 = row0 & 1023;
                    bf16x4 w;
#pragma unroll
                    for (int rg = 0; rg < 4; rg++) w[rg] = (bf16_t)(acc[tr][tc][rg] + bv);
                    *reinterpret_cast<bf16x4*>(
                        vTo + ((size_t)(b * HEADS + head) * DHEAD + dd) * SEQ + nn0) = w;
                }
            }
        } else {
            bf16_t* dst = (whichb == 0) ? qo : (whichb == 1) ? ko : ro;
#pragma unroll
            for (int tr = 0; tr < 4; tr++) {
#pragma unroll
                for (int tc = 0; tc < 4; tc++) {
                    const int hd   = (bx % 6) * 128 + wn * 64 + tc * 16 + col16;
                    const int head = hd / DHEAD, dd = hd % DHEAD;
                    const float bv = bias[hd * 4 + whichb];
#pragma unroll
                    for (int rg = 0; rg < 4; rg++) {
                        const int row = m0 + wm * 64 + tr * 16 + quad * 4 + rg;
                        const int b = row >> 10, nn = row & 1023;
                        dst[((size_t)(b * HEADS + head) * SEQ + nn) * DHEAD + dd] =
                            (bf16_t)(acc[tr][tc][rg] + bv);
                    }
                }
            }
        }
    } else {
#pragma unroll
        for (int tr = 0; tr < 4; tr++) {
#pragma unroll
            for (int tc = 0; tc < 4; tc++) {
#pragma unroll
                for (int rg = 0; rg < 4; rg++) {
                    const int row  = m0 + wm * 64 + tr * 16 + quad * 4 + rg;
                    const int colg = n0 + wn * 64 + tc * 16 + col16;
                    float v = acc[tr][tc][rg] + bias[colg];
                    if (EPI == EPI_PROJ || EPI == EPI_FF2) {
                        outf[(size_t)row * EMB + colg] = v + resid[(size_t)row * EMB + colg];
                    } else {  // EPI_GELU: tanh-form gelu via sigmoid (|err|<3e-3 vs erf)
                        const float z = 1.5957691216057308f * v * (1.0f + 0.044715f * v * v);
                        const float g = v / (1.0f + __expf(-z));
                        outb[(size_t)row * 3072 + colg] = (bf16_t)g;
                    }
                }
            }
        }
    }
}

// ---------------------------------------------------------------- attention
// (unchanged)

__global__ __launch_bounds__(256) void attn_kernel(
    const bf16_t* __restrict__ q, const bf16_t* __restrict__ k,
    const bf16_t* __restrict__ vT, const bf16_t* __restrict__ r,
    bf16_t* __restrict__ attn_out)
{
    __shared__ __align__(16) bf16_t Ks[64 * 96];    // [key][dim]
    __shared__ __align__(16) bf16_t Vs[96 * 64];    // [feat][16B-unit swizzled by feat&7]
    __shared__ __align__(16) bf16_t P[4][16 * 72];  // wave-private P (barriers protect reuse)

    const int tid = threadIdx.x, wave = tid >> 6, lane = tid & 63;
    const int quad = lane >> 4, col = lane & 15;
    const int bh = blockIdx.x & 63, qb = blockIdx.x >> 6;
    const int n0 = qb * 64 + wave * 16;
    const bf16_t* qp = q  + (size_t)bh * SEQ * DHEAD;
    const bf16_t* kb = k  + (size_t)bh * SEQ * DHEAD;
    const bf16_t* vb = vT + (size_t)bh * DHEAD * SEQ;
    bf16_t* Pw = P[wave];

    bf16x8 qf[3];  // Q as B-operand: B[k=dim][n=q-row]
#pragma unroll
    for (int ks = 0; ks < 3; ks++)
        qf[ks] = *reinterpret_cast<const bf16x8*>(qp + (size_t)(n0 + col) * DHEAD + ks * 32 + quad * 8);

    // staging unit ids (16B units): K has 64*12=768, V has 96*8=768
    const int u0 = tid, u1 = tid + 256, u2 = tid + 512;
    const int vf0 = u0 >> 3, vp0 = (u0 & 7) ^ (vf0 & 7);
    const int vf1 = u1 >> 3, vp1 = (u1 & 7) ^ (vf1 & 7);
    const int vf2 = u2 >> 3, vp2 = (u2 & 7) ^ (vf2 & 7);

    f32x4 O[6] = {};
    float lsum = 0.f;  // per-lane partial row-sum for q-row `col`

    for (int ch = 0; ch < SEQ / 64; ch++) {
        const int kc0 = ch * 64;
        __syncthreads();  // all waves done reading Ks/Vs of previous chunk
        const bf16_t* ksrc = kb + (size_t)kc0 * DHEAD;  // 64 keys x 96 dims, contiguous
        load16_lds(ksrc + u0 * 8, Ks + u0 * 8);
        load16_lds(ksrc + u1 * 8, Ks + u1 * 8);
        load16_lds(ksrc + u2 * 8, Ks + u2 * 8);
        load16_lds(vb + (size_t)vf0 * SEQ + kc0 + vp0 * 8, Vs + u0 * 8);
        load16_lds(vb + (size_t)vf1 * SEQ + kc0 + vp1 * 8, Vs + u1 * 8);
        load16_lds(vb + (size_t)vf2 * SEQ + kc0 + vp2 * 8, Vs + u2 * 8);
        __syncthreads();  // compiler drains vmcnt before barrier: tiles ready

        f32x4 s[4] = {};
#pragma unroll
        for (int ks = 0; ks < 3; ks++) {  // K as A-operand: A[m=key][k=dim]
#pragma unroll
            for (int h = 0; h < 4; h++) {
                bf16x8 kf = *reinterpret_cast<const bf16x8*>(Ks + (h * 16 + col) * DHEAD + ks * 32 + quad * 8);
                s[h] = __builtin_amdgcn_mfma_f32_16x16x32_bf16(kf, qf[ks], s[h], 0, 0, 0);
            }
        }
        // S^T C-layout: lane holds keys h*16+quad*4+rg for q-row `col`
#pragma unroll
        for (int h = 0; h < 4; h++) {
            bf16x4 w;
#pragma unroll
            for (int rg = 0; rg < 4; rg++) {
                const float e = __expf(s[h][rg]);
                lsum += e;
                w[rg] = (bf16_t)e;
            }
            *reinterpret_cast<bf16x4*>(Pw + col * 72 + h * 16 + quad * 4) = w;
        }
        // A-operand read back: A[m=q-row=col][k=key]
        bf16x8 af0 = *reinterpret_cast<const bf16x8*>(Pw + col * 72 + quad * 8);
        bf16x8 af1 = *reinterpret_cast<const bf16x8*>(Pw + col * 72 + 32 + quad * 8);
#pragma unroll
        for (int tc = 0; tc < 6; tc++) {  // V as B-operand: B[k=key][n=feat]
            const int feat = tc * 16 + col;
            bf16x8 bv0 = *reinterpret_cast<const bf16x8*>(Vs + feat * 64 + ((quad)     ^ (col & 7)) * 8);
            bf16x8 bv1 = *reinterpret_cast<const bf16x8*>(Vs + feat * 64 + ((4 + quad) ^ (col & 7)) * 8);
            O[tc] = __builtin_amdgcn_mfma_f32_16x16x32_bf16(af0, bv0, O[tc], 0, 0, 0);
            O[tc] = __builtin_amdgcn_mfma_f32_16x16x32_bf16(af1, bv1, O[tc], 0, 0, 0);
        }
    }

    // finalize row sums: reduce over quads (lanes sharing `col`)
    lsum += __shfl_xor(lsum, 16);
    lsum += __shfl_xor(lsum, 32);

    const float inv_sqrt_emb = 0.036084391824351615f;  // 1/sqrt(768)
    const int b = bh >> 3, h = bh & 7;
#pragma unroll
    for (int rg = 0; rg < 4; rg++) {
        const int nrow = quad * 4 + rg;
        const float lr = __shfl(lsum, nrow);  // lane nrow holds q-row nrow's sum
        const float scale = inv_sqrt_emb / lr;
        const int n = n0 + nrow;
#pragma unroll
        for (int tc = 0; tc < 6; tc++) {
            const int feat = tc * 16 + col;
            const float rv = (float)r[((size_t)bh * SEQ + n) * DHEAD + feat];
            attn_out[((size_t)(b * SEQ + n)) * EMB + h * DHEAD + feat] = (bf16_t)(O[tc][rg] * scale * rv);
        }
    }
}

// ---------------------------------------------------------------- LayerNorm (row=768)

__global__ __launch_bounds__(256) void ln_kernel(
    const float* __restrict__ in, const float* __restrict__ g, const float* __restrict__ b,
    float* __restrict__ y, bf16_t* __restrict__ yb)
{
    const int row = blockIdx.x * 4 + (threadIdx.x >> 6);
    const int lane = threadIdx.x & 63;
    const float* rp = in + (size_t)row * EMB;
    float v[12];
    float sum = 0.f;
#pragma unroll
    for (int i = 0; i < 12; i++) { v[i] = rp[lane + i * 64]; sum += v[i]; }
#pragma unroll
    for (int off = 32; off; off >>= 1) sum += __shfl_xor(sum, off);
    const float mean = sum * (1.0f / 768.0f);
    float s2 = 0.f;
#pragma unroll
    for (int i = 0; i < 12; i++) { float d = v[i] - mean; s2 += d * d; }
#pragma unroll
    for (int off = 32; off; off >>= 1) s2 += __shfl_xor(s2, off);
    const float inv = rsqrtf(s2 * (1.0f / 768.0f) + 1e-5f);
#pragma unroll
    for (int i = 0; i < 12; i++) {
        const int c = lane + i * 64;
        const float o = (v[i] - mean) * inv * g[c] + b[c];
        y[(size_t)row * EMB + c] = o;
        if (yb) yb[(size_t)row * EMB + c] = (bf16_t)o;
    }
}

// ---------------------------------------------------------------- launch

extern "C" void kernel_launch(void* const* d_in, const int* in_sizes, int n_in,
                              void* d_out, int out_size, void* d_ws, size_t ws_size,
                              hipStream_t stream)
{
    const float* x      = (const float*)d_in[0];
    const float* w_qkvr = (const float*)d_in[1];
    const float* b_qkvr = (const float*)d_in[2];
    const float* w_proj = (const float*)d_in[3];
    const float* b_proj = (const float*)d_in[4];
    const float* ln1_g  = (const float*)d_in[5];
    const float* ln1_b  = (const float*)d_in[6];
    const float* w_ff1  = (const float*)d_in[7];
    const float* b_ff1  = (const float*)d_in[8];
    const float* w_ff2  = (const float*)d_in[9];
    const float* b_ff2  = (const float*)d_in[10];
    const float* ln2_g  = (const float*)d_in[11];
    const float* ln2_b  = (const float*)d_in[12];
    float* out = (float*)d_out;

    char* ws = (char*)d_ws;
    size_t off = 0;
    auto alloc = [&](size_t bytes) {
        char* p = ws + off;
        off += (bytes + 255) & ~(size_t)255;
        return (void*)p;
    };
    const size_t ACT = (size_t)ROWS * EMB;  // 6291456
    bf16_t* xb      = (bf16_t*)alloc(ACT * 2);
    bf16_t* wqkvrT  = (bf16_t*)alloc((size_t)3072 * 768 * 2);
    bf16_t* wprojT  = (bf16_t*)alloc((size_t)768 * 768 * 2);
    bf16_t* wff1T   = (bf16_t*)alloc((size_t)3072 * 768 * 2);
    bf16_t* wff2T   = (bf16_t*)alloc((size_t)768 * 3072 * 2);
    bf16_t* qbuf    = (bf16_t*)alloc(ACT * 2);
    bf16_t* kbuf    = (bf16_t*)alloc(ACT * 2);
    bf16_t* vTbuf   = (bf16_t*)alloc(ACT * 2);
    bf16_t* rbuf    = (bf16_t*)alloc(ACT * 2);
    bf16_t* attn_o  = (bf16_t*)alloc(ACT * 2);
    float*  x1f     = (float*)alloc(ACT * 4);
    bf16_t* x1b     = (bf16_t*)alloc(ACT * 2);
    bf16_t* ff1     = (bf16_t*)alloc((size_t)ROWS * 3072 * 2);
    float*  res     = out;  // d_out doubles as fp32 residual scratch

    dim3 tb32(32, 8);

    cvt_bf16_kernel<<<2048, 256, 0, stream>>>(x, xb, (int)ACT);
    qkvr_transpose_kernel<<<dim3(3072 / 32, 768 / 32), tb32, 0, stream>>>(w_qkvr, wqkvrT);
    transpose_cvt_kernel<<<dim3(768 / 32, 768 / 32), tb32, 0, stream>>>(w_proj, wprojT, 768, 768);
    transpose_cvt_kernel<<<dim3(3072 / 32, 768 / 32), tb32, 0, stream>>>(w_ff1, wff1T, 768, 3072);
    transpose_cvt_kernel<<<dim3(768 / 32, 3072 / 32), tb32, 0, stream>>>(w_ff2, wff2T, 3072, 768);

    // QKVR: M=8192, N=3072 -> 32 x 24 = 768 blocks (3 clean CU-rounds)
    gemm8p_kernel<EPI_QKVR, 768, 24><<<768, 512, 0, stream>>>(
        xb, wqkvrT, b_qkvr, qbuf, kbuf, vTbuf, rbuf, nullptr, nullptr, nullptr);

    attn_kernel<<<dim3(SEQ / 64 * BATCH * HEADS), 256, 0, stream>>>(qbuf, kbuf, vTbuf, rbuf, attn_o);

    // PROJ: M=8192, N=768 -> 32 x 6 = 192 blocks
    gemm8p_kernel<EPI_PROJ, 768, 6><<<192, 512, 0, stream>>>(
        attn_o, wprojT, b_proj, nullptr, nullptr, nullptr, nullptr, x, res, nullptr);
    ln_kernel<<<2048, 256, 0, stream>>>(res, ln1_g, ln1_b, x1f, x1b);

    // FF1+GELU: M=8192, N=3072
    gemm8p_kernel<EPI_GELU, 768, 24><<<768, 512, 0, stream>>>(
        x1b, wff1T, b_ff1, nullptr, nullptr, nullptr, nullptr, nullptr, nullptr, ff1);

    // FF2: M=8192, N=768, K=3072
    gemm8p_kernel<EPI_FF2, 3072, 6><<<192, 512, 0, stream>>>(
        ff1, wff2T, b_ff2, nullptr, nullptr, nullptr, nullptr, x1f, res, nullptr);
    ln_kernel<<<2048, 256, 0, stream>>>(res, ln2_g, ln2_b, out, nullptr);

    (void)in_sizes; (void)n_in; (void)out_size; (void)ws_size;
}